// Round 1
// baseline (338.886 us; speedup 1.0000x reference)
//
#include <hip/hip_runtime.h>
#include <math.h>

#define B_DIM 8
#define T_DIM 2048
#define C_DIM 1024
#define H_DIM 64
#define NG 64
#define NR 64
#define M_TOTAL (B_DIM * T_DIM)   // 16384 rows
#define NQKV 192                  // k(0..63) | q(64..127) | v(128..191)

// ---------------------------------------------------------------------------
// Kernel 1: fused QKV projection.  qkv[m][n] = sum_c x[m][c] * W[n][c]
// Tile: 64 rows x 64 cols per block, K-chunks of 16 staged in LDS (k-major
// so compute reads are ds_read_b128).  Grid (M/64, 3): y picks Wk/Wq/Wv.
// ---------------------------------------------------------------------------
__global__ __launch_bounds__(256) void proj_kernel(
    const float* __restrict__ x,
    const float* __restrict__ Wk,
    const float* __restrict__ Wq,
    const float* __restrict__ Wv,
    float* __restrict__ qkv)
{
    __shared__ float Xs[16][68];   // [k][row], pad 68 to break bank strides
    __shared__ float Ws[16][68];   // [k][col]

    const int m0   = blockIdx.x * 64;
    const int ncol = blockIdx.y;           // 0=k, 1=q, 2=v
    const float* __restrict__ Wp = (ncol == 0) ? Wk : ((ncol == 1) ? Wq : Wv);

    const int tid = threadIdx.x;
    const int tx  = tid & 15;              // col group
    const int ty  = tid >> 4;              // row group
    const int r   = tid >> 2;              // load row 0..63
    const int cq  = tid & 3;               // load k-quad 0..3

    float acc[4][4];
    #pragma unroll
    for (int i = 0; i < 4; i++)
        #pragma unroll
        for (int j = 0; j < 4; j++) acc[i][j] = 0.f;

    for (int kc = 0; kc < C_DIM; kc += 16) {
        float4 xv = *(const float4*)&x [(size_t)(m0 + r) * C_DIM + kc + cq * 4];
        float4 wv = *(const float4*)&Wp[(size_t)r        * C_DIM + kc + cq * 4];
        __syncthreads();   // previous chunk's reads done before overwrite
        Xs[cq*4+0][r] = xv.x; Xs[cq*4+1][r] = xv.y;
        Xs[cq*4+2][r] = xv.z; Xs[cq*4+3][r] = xv.w;
        Ws[cq*4+0][r] = wv.x; Ws[cq*4+1][r] = wv.y;
        Ws[cq*4+2][r] = wv.z; Ws[cq*4+3][r] = wv.w;
        __syncthreads();
        #pragma unroll
        for (int k = 0; k < 16; k++) {
            float4 a = *(const float4*)&Xs[k][ty * 4];
            float4 b = *(const float4*)&Ws[k][tx * 4];
            float av[4] = {a.x, a.y, a.z, a.w};
            float bv[4] = {b.x, b.y, b.z, b.w};
            #pragma unroll
            for (int i = 0; i < 4; i++)
                #pragma unroll
                for (int j = 0; j < 4; j++)
                    acc[i][j] = fmaf(av[i], bv[j], acc[i][j]);
        }
    }

    #pragma unroll
    for (int i = 0; i < 4; i++) {
        float4 o = make_float4(acc[i][0], acc[i][1], acc[i][2], acc[i][3]);
        *(float4*)&qkv[(size_t)(m0 + ty * 4 + i) * NQKV + ncol * 64 + tx * 4] = o;
    }
}

// ---------------------------------------------------------------------------
// Kernel 2: sparse BigBird attention. One block per (b, i) query row.
// Bitmap over T columns gives exact boolean-union mask semantics.
// ---------------------------------------------------------------------------
__global__ __launch_bounds__(256) void attn_kernel(
    const float* __restrict__ qkv,
    const int*   __restrict__ rnd,      // [T][NR]
    float* __restrict__ out)            // [B][T][H]
{
    const int bi = blockIdx.x;          // 0..M_TOTAL-1
    const int b  = bi >> 11;            // / T_DIM
    const int i  = bi & (T_DIM - 1);

    __shared__ unsigned bitmap[64];     // 2048 bits
    __shared__ int      cnts[64];
    __shared__ int      collist[256];   // max 192 unique cols
    __shared__ float    scores[256];
    __shared__ float    red[256];
    __shared__ float    qs[64];
    __shared__ float    partial[4][64];
    __shared__ int      s_ncols;

    const int t = threadIdx.x;

    if (t < 64) bitmap[t] = 0u;
    __syncthreads();

    // set mask bits (all causal-filtered)
    if (t < 64) {                                   // local window: j = i-t
        int j = i - t;
        if (j >= 0) atomicOr(&bitmap[j >> 5], 1u << (j & 31));
    } else if (t < 128) {                           // global cols j < 64
        int j = t - 64;
        if (j <= i) atomicOr(&bitmap[j >> 5], 1u << (j & 31));
    } else if (t < 192) {                           // random cols
        int j = rnd[i * NR + (t - 128)];
        if (j <= i) atomicOr(&bitmap[j >> 5], 1u << (j & 31));
    }
    __syncthreads();

    if (t < 64) cnts[t] = __popc(bitmap[t]);
    if (t < 64) qs[t] = qkv[(size_t)bi * NQKV + 64 + t];   // q row
    __syncthreads();

    // compact bitmap -> column list
    if (t < 64) {
        int off = 0;
        for (int w = 0; w < t; w++) off += cnts[w];
        unsigned m = bitmap[t];
        while (m) {
            int bit = __ffs(m) - 1;
            m &= m - 1;
            collist[off++] = t * 32 + bit;
        }
        if (t == 63) s_ncols = off;
    }
    __syncthreads();
    const int ncols = s_ncols;

    // scores: one column per thread
    float sc = -INFINITY;
    if (t < ncols) {
        int j = collist[t];
        const float* krow = &qkv[(size_t)(b * T_DIM + j) * NQKV];
        float s = 0.f;
        #pragma unroll
        for (int h = 0; h < H_DIM; h += 4) {
            float4 kv = *(const float4*)&krow[h];
            s = fmaf(qs[h + 0], kv.x, s);
            s = fmaf(qs[h + 1], kv.y, s);
            s = fmaf(qs[h + 2], kv.z, s);
            s = fmaf(qs[h + 3], kv.w, s);
        }
        sc = s * 0.125f;   // 1/sqrt(64)
    }
    scores[t] = sc;
    red[t]    = sc;
    __syncthreads();

    // max reduce
    #pragma unroll
    for (int s2 = 128; s2 > 0; s2 >>= 1) {
        if (t < s2) red[t] = fmaxf(red[t], red[t + s2]);
        __syncthreads();
    }
    const float mx = red[0];
    __syncthreads();

    float e = (t < ncols) ? __expf(scores[t] - mx) : 0.f;
    scores[t] = e;
    red[t]    = e;
    __syncthreads();

    // sum reduce
    #pragma unroll
    for (int s2 = 128; s2 > 0; s2 >>= 1) {
        if (t < s2) red[t] += red[t + s2];
        __syncthreads();
    }
    const float l = red[0];

    // PV: 4 groups of 64 threads, strided over columns
    const int g = t >> 6;
    const int h = t & 63;
    float acc = 0.f;
    for (int n = g; n < ncols; n += 4) {
        const float* vrow = &qkv[(size_t)(b * T_DIM + collist[n]) * NQKV + 128];
        acc = fmaf(scores[n], vrow[h], acc);
    }
    partial[g][h] = acc;
    __syncthreads();

    if (t < 64) {
        float o = (partial[0][t] + partial[1][t] + partial[2][t] + partial[3][t]) / l;
        out[(size_t)bi * H_DIM + t] = o;
    }
}

// ---------------------------------------------------------------------------
extern "C" void kernel_launch(void* const* d_in, const int* in_sizes, int n_in,
                              void* d_out, int out_size, void* d_ws, size_t ws_size,
                              hipStream_t stream) {
    const float* x   = (const float*)d_in[0];
    const int*   rnd = (const int*)  d_in[1];
    const float* Wk  = (const float*)d_in[2];
    const float* Wq  = (const float*)d_in[3];
    const float* Wv  = (const float*)d_in[4];
    float* out = (float*)d_out;
    float* qkv = (float*)d_ws;   // 16384 * 192 * 4 B = 12.6 MB

    dim3 g1(M_TOTAL / 64, 3);
    proj_kernel<<<g1, 256, 0, stream>>>(x, Wk, Wq, Wv, qkv);
    attn_kernel<<<M_TOTAL, 256, 0, stream>>>(qkv, rnd, out);
}

// Round 2
// 216.753 us; speedup vs baseline: 1.5635x; 1.5635x over previous
//
#include <hip/hip_runtime.h>
#include <math.h>

#define T_DIM 2048
#define C_DIM 1024
#define H_DIM 64
#define M_TOTAL 16384            // B*T
#define NQKV 192                 // k(0..63) | q(64..127) | v(128..191)

typedef __bf16 bf16x8 __attribute__((ext_vector_type(8)));
typedef float f32x4 __attribute__((ext_vector_type(4)));
typedef unsigned short u16x8 __attribute__((ext_vector_type(8)));

__device__ __forceinline__ unsigned short f2bf(float f) {
    unsigned u = __float_as_uint(f);
    unsigned r = (u + 0x7FFFu + ((u >> 16) & 1u)) >> 16;   // RNE
    return (unsigned short)r;
}
__device__ __forceinline__ float bf2f(unsigned short u) {
    return __uint_as_float(((unsigned)u) << 16);
}

// ---------------------------------------------------------------------------
// Kernel 1: QKV projection as bf16 MFMA GEMM.
// C[16384x192] = x[16384x1024] . W^T, W rows are K-major (perfect MFMA B).
// Block = 64 rows x 64 cols (by picks Wk/Wq/Wv), 4 waves, wave = 16x64 strip.
// fp32 -> bf16 conversion fused into LDS staging. Output qkv is bf16.
// ---------------------------------------------------------------------------
__global__ __launch_bounds__(256) void proj_kernel(
    const float* __restrict__ x,
    const float* __restrict__ Wk,
    const float* __restrict__ Wq,
    const float* __restrict__ Wv,
    unsigned short* __restrict__ qkv)   // [16384][192] bf16 bits
{
    __shared__ unsigned short Ab[64 * 64];   // [row][k] k-contiguous
    __shared__ unsigned short Bb[64 * 64];   // [col][k]

    const int m0 = blockIdx.x * 64;
    const int by = blockIdx.y;
    const float* __restrict__ W = (by == 0) ? Wk : ((by == 1) ? Wq : Wv);

    const int t  = threadIdx.x;
    const int wv = t >> 6;          // wave id 0..3 (row strip)
    const int ln = t & 63;
    const int mfr = ln & 15;        // fragment m/n index
    const int kq  = ln >> 4;        // fragment k-quad 0..3

    f32x4 acc[4] = {};

    for (int kc = 0; kc < C_DIM; kc += 64) {
        // ---- load 2 units of 8 floats each from x and W into registers ----
        float4 fx[2][2], fw[2][2];
        #pragma unroll
        for (int it = 0; it < 2; ++it) {
            int u   = it * 256 + t;          // 0..511
            int row = u >> 3;                // 0..63
            int k8  = (u & 7) * 8;
            const float* gx = &x[(size_t)(m0 + row) * C_DIM + kc + k8];
            fx[it][0] = *(const float4*)gx;
            fx[it][1] = *(const float4*)(gx + 4);
            const float* gw = &W[(size_t)row * C_DIM + kc + k8];
            fw[it][0] = *(const float4*)gw;
            fw[it][1] = *(const float4*)(gw + 4);
        }
        __syncthreads();   // previous chunk's compute reads done
        #pragma unroll
        for (int it = 0; it < 2; ++it) {
            int u   = it * 256 + t;
            int row = u >> 3;
            int k8  = (u & 7) * 8;
            u16x8 av, bv;
            av[0] = f2bf(fx[it][0].x); av[1] = f2bf(fx[it][0].y);
            av[2] = f2bf(fx[it][0].z); av[3] = f2bf(fx[it][0].w);
            av[4] = f2bf(fx[it][1].x); av[5] = f2bf(fx[it][1].y);
            av[6] = f2bf(fx[it][1].z); av[7] = f2bf(fx[it][1].w);
            bv[0] = f2bf(fw[it][0].x); bv[1] = f2bf(fw[it][0].y);
            bv[2] = f2bf(fw[it][0].z); bv[3] = f2bf(fw[it][0].w);
            bv[4] = f2bf(fw[it][1].x); bv[5] = f2bf(fw[it][1].y);
            bv[6] = f2bf(fw[it][1].z); bv[7] = f2bf(fw[it][1].w);
            *(u16x8*)&Ab[row * 64 + k8] = av;
            *(u16x8*)&Bb[row * 64 + k8] = bv;
        }
        __syncthreads();
        // ---- MFMA over the 64-K chunk (two k32 steps) ----
        #pragma unroll
        for (int ks = 0; ks < 64; ks += 32) {
            bf16x8 af = *(const bf16x8*)&Ab[(wv * 16 + mfr) * 64 + ks + kq * 8];
            #pragma unroll
            for (int ct = 0; ct < 4; ++ct) {
                bf16x8 bfv = *(const bf16x8*)&Bb[(ct * 16 + mfr) * 64 + ks + kq * 8];
                acc[ct] = __builtin_amdgcn_mfma_f32_16x16x32_bf16(af, bfv, acc[ct], 0, 0, 0);
            }
        }
    }

    // epilogue: C layout col=lane&15, row=(lane>>4)*4+reg
    const int n0 = by * 64;
    #pragma unroll
    for (int ct = 0; ct < 4; ++ct) {
        #pragma unroll
        for (int r = 0; r < 4; ++r) {
            int row = m0 + wv * 16 + kq * 4 + r;
            int col = n0 + ct * 16 + mfr;
            qkv[(size_t)row * NQKV + col] = f2bf(acc[ct][r]);
        }
    }
}

// ---------------------------------------------------------------------------
// Kernel 2: sparse BigBird attention, one wave per query row, 4 rows/block.
// Candidates: lane l owns {local i-l, global l, random rnd[i][l]} with
// closed-form dedup. Branch-free scores + wave-shuffle softmax + coalesced
// h-parallel PV.
// ---------------------------------------------------------------------------
__global__ __launch_bounds__(256) void attn_kernel(
    const unsigned short* __restrict__ qkv,   // bf16 bits [16384][192]
    const int*  __restrict__ rnd,             // [2048][64]
    float* __restrict__ out)                  // [16384][64]
{
    const int wv = threadIdx.x >> 6;
    const int ln = threadIdx.x & 63;
    const int bi = blockIdx.x * 4 + wv;
    const int b  = bi >> 11;
    const int i  = bi & (T_DIM - 1);

    __shared__ float qs_all[4][64];
    __shared__ int2  cl_all[4][192];
    float* qs = qs_all[wv];
    int2*  cl = cl_all[wv];

    // q row (bf16 -> fp32) into per-wave LDS
    qs[ln] = bf2f(qkv[(size_t)bi * NQKV + 64 + ln]);

    // candidate columns (clamped in-range so loads are always safe)
    int  j0 = i - ln;            bool v0 = (j0 >= 0); if (!v0) j0 = 0;
    int  j1 = ln;                bool v1 = (j1 < i - 63);
    int  j2 = rnd[i * 64 + ln];  bool v2 = (j2 < i - 63) && (j2 >= 64);
    // dedup among randoms: first occurrence wins
    for (int p = 0; p < 64; ++p) {
        int o = __shfl(j2, p);
        if (p < ln && o == j2) v2 = false;
    }
    __syncthreads();   // qs visible to all lanes

    // ---- QK^T scores (candidate-parallel, branch-free) ----
    const unsigned short* kb = qkv + (size_t)b * T_DIM * NQKV;
    const unsigned short* k0 = kb + (size_t)j0 * NQKV;
    const unsigned short* k1 = kb + (size_t)j1 * NQKV;
    const unsigned short* k2 = kb + (size_t)j2 * NQKV;
    float s0 = 0.f, s1 = 0.f, s2 = 0.f;
    #pragma unroll
    for (int h = 0; h < H_DIM; h += 8) {
        u16x8 a0 = *(const u16x8*)(k0 + h);
        u16x8 a1 = *(const u16x8*)(k1 + h);
        u16x8 a2 = *(const u16x8*)(k2 + h);
        #pragma unroll
        for (int e = 0; e < 8; ++e) {
            float qv = qs[h + e];
            s0 = fmaf(qv, bf2f(a0[e]), s0);
            s1 = fmaf(qv, bf2f(a1[e]), s1);
            s2 = fmaf(qv, bf2f(a2[e]), s2);
        }
    }
    s0 = v0 ? s0 * 0.125f : -1e30f;
    s1 = v1 ? s1 * 0.125f : -1e30f;
    s2 = v2 ? s2 * 0.125f : -1e30f;

    // ---- online softmax over the wave ----
    float mx = fmaxf(s0, fmaxf(s1, s2));
    #pragma unroll
    for (int m = 32; m; m >>= 1) mx = fmaxf(mx, __shfl_xor(mx, m));
    float e0 = v0 ? __expf(s0 - mx) : 0.f;
    float e1 = v1 ? __expf(s1 - mx) : 0.f;
    float e2 = v2 ? __expf(s2 - mx) : 0.f;
    float sum = e0 + e1 + e2;
    #pragma unroll
    for (int m = 32; m; m >>= 1) sum += __shfl_xor(sum, m);

    cl[ln]        = make_int2(j0, __float_as_int(e0));
    cl[64 + ln]   = make_int2(j1, __float_as_int(e1));
    cl[128 + ln]  = make_int2(j2, __float_as_int(e2));
    __syncthreads();   // cl visible

    // ---- PV (h-parallel: lane = h, coalesced 128B v reads per column) ----
    const unsigned short* vcol = kb + 128 + ln;
    float acc = 0.f;
    #pragma unroll 8
    for (int c = 0; c < 192; ++c) {
        int2 p = cl[c];
        float w = __int_as_float(p.y);
        acc = fmaf(w, bf2f(vcol[(size_t)p.x * NQKV]), acc);
    }
    out[(size_t)bi * H_DIM + ln] = acc / sum;
}

// ---------------------------------------------------------------------------
extern "C" void kernel_launch(void* const* d_in, const int* in_sizes, int n_in,
                              void* d_out, int out_size, void* d_ws, size_t ws_size,
                              hipStream_t stream) {
    const float* x   = (const float*)d_in[0];
    const int*   rnd = (const int*)  d_in[1];
    const float* Wk  = (const float*)d_in[2];
    const float* Wq  = (const float*)d_in[3];
    const float* Wv  = (const float*)d_in[4];
    float* out = (float*)d_out;
    unsigned short* qkv = (unsigned short*)d_ws;   // 16384*192*2 = 6.3 MB bf16

    dim3 g1(M_TOTAL / 64, 3);
    proj_kernel<<<g1, 256, 0, stream>>>(x, Wk, Wq, Wv, qkv);
    attn_kernel<<<M_TOTAL / 4, 256, 0, stream>>>(qkv, rnd, out);
}

// Round 3
// 189.590 us; speedup vs baseline: 1.7875x; 1.1433x over previous
//
#include <hip/hip_runtime.h>
#include <math.h>

#define T_DIM 2048
#define C_DIM 1024
#define H_DIM 64
#define M_TOTAL 16384            // B*T
#define NQKV 192                 // k(0..63) | q(64..127) | v(128..191)

typedef __bf16 bf16x8 __attribute__((ext_vector_type(8)));
typedef float f32x4 __attribute__((ext_vector_type(4)));
typedef unsigned short u16x8 __attribute__((ext_vector_type(8)));

__device__ __forceinline__ unsigned short f2bf(float f) {
    unsigned u = __float_as_uint(f);
    unsigned r = (u + 0x7FFFu + ((u >> 16) & 1u)) >> 16;   // RNE
    return (unsigned short)r;
}
__device__ __forceinline__ float bf2f(unsigned short u) {
    return __uint_as_float(((unsigned)u) << 16);
}
__device__ __forceinline__ void glds16(const void* g, void* l) {
    __builtin_amdgcn_global_load_lds((const __attribute__((address_space(1))) void*)g,
                                     (__attribute__((address_space(3))) void*)l, 16, 0, 0);
}

// ---------------------------------------------------------------------------
// Kernel 0: fp32 -> bf16 conversion of x (16.7M) and Wk|Wq|Wv (into Wall[192][1024]).
// Pure memory-bound (~100 MB).
// ---------------------------------------------------------------------------
#define X_THREADS (M_TOTAL * C_DIM / 8)            // 2097152
#define W_THREADS (NQKV * C_DIM / 8)               // 24576
__global__ __launch_bounds__(256) void convert_kernel(
    const float* __restrict__ x,
    const float* __restrict__ Wk,
    const float* __restrict__ Wq,
    const float* __restrict__ Wv,
    unsigned short* __restrict__ xb,
    unsigned short* __restrict__ Wall)
{
    const int gid = blockIdx.x * 256 + threadIdx.x;
    const float* src;
    unsigned short* dst;
    if (gid < X_THREADS) {
        size_t f = (size_t)gid * 8;
        src = x + f;
        dst = xb + f;
    } else {
        size_t f = (size_t)(gid - X_THREADS) * 8;
        int row = (int)(f >> 10);
        int col = (int)(f & 1023);
        const float* W = (row < 64) ? (Wk + row * C_DIM)
                       : (row < 128) ? (Wq + (row - 64) * C_DIM)
                                     : (Wv + (row - 128) * C_DIM);
        src = W + col;
        dst = Wall + (size_t)row * C_DIM + col;
    }
    float4 a = *(const float4*)src;
    float4 b = *(const float4*)(src + 4);
    u16x8 o;
    o[0] = f2bf(a.x); o[1] = f2bf(a.y); o[2] = f2bf(a.z); o[3] = f2bf(a.w);
    o[4] = f2bf(b.x); o[5] = f2bf(b.y); o[6] = f2bf(b.z); o[7] = f2bf(b.w);
    *(u16x8*)dst = o;
}

// ---------------------------------------------------------------------------
// Kernel 1 (fast path): bf16 MFMA GEMM with global_load_lds staging.
// C[16384x192] = xb . Wall^T.  Block: 64 rows x 96 cols, BK=64, 4 waves,
// wave = 32x96 (2x3 tiles).  Grid (256, 2).
// ---------------------------------------------------------------------------
__global__ __launch_bounds__(256) void proj_glds_kernel(
    const unsigned short* __restrict__ xb,
    const unsigned short* __restrict__ Wall,
    unsigned short* __restrict__ qkv)
{
    __shared__ unsigned short Ab[64 * 64];   // [row][k]
    __shared__ unsigned short Bb[96 * 64];   // [col][k]

    const int m0  = blockIdx.x * 64;
    const int n0g = blockIdx.y * 96;

    const int t   = threadIdx.x;
    const int wv  = t >> 6;
    const int ln  = t & 63;
    const int mfr = ln & 15;
    const int kq  = ln >> 4;
    const int r0  = (wv & 1) * 32;           // wave row base
    const int c0  = (wv >> 1) * 48;          // wave col base (within 96)

    const int sub = ln >> 3;                 // 0..7 (row within 8-row slab)
    const int k8  = (ln & 7) * 8;            // k offset (elems)

    f32x4 acc[2][3] = {};

    for (int kc = 0; kc < C_DIM; kc += 64) {
        __syncthreads();   // all waves done reading previous chunk
        #pragma unroll
        for (int s = 0; s < 5; ++s) {
            int u = wv * 5 + s;              // 0..19: 8 A-slabs + 12 B-slabs
            if (u < 8) {
                int row = u * 8 + sub;
                glds16(&xb[(size_t)(m0 + row) * C_DIM + kc + k8],
                       &Ab[(u * 8) * 64 + ln * 8]);
            } else {
                int row = (u - 8) * 8 + sub;
                glds16(&Wall[(size_t)(n0g + row) * C_DIM + kc + k8],
                       &Bb[((u - 8) * 8) * 64 + ln * 8]);
            }
        }
        __syncthreads();   // barrier drains vmcnt -> LDS filled
        #pragma unroll
        for (int ks = 0; ks < 64; ks += 32) {
            bf16x8 af[2], bf[3];
            #pragma unroll
            for (int a = 0; a < 2; ++a)
                af[a] = *(const bf16x8*)&Ab[(r0 + a * 16 + mfr) * 64 + ks + kq * 8];
            #pragma unroll
            for (int b2 = 0; b2 < 3; ++b2)
                bf[b2] = *(const bf16x8*)&Bb[(c0 + b2 * 16 + mfr) * 64 + ks + kq * 8];
            #pragma unroll
            for (int a = 0; a < 2; ++a)
                #pragma unroll
                for (int b2 = 0; b2 < 3; ++b2)
                    acc[a][b2] = __builtin_amdgcn_mfma_f32_16x16x32_bf16(
                        af[a], bf[b2], acc[a][b2], 0, 0, 0);
        }
    }

    // epilogue: C layout col=lane&15, row=(lane>>4)*4+reg
    #pragma unroll
    for (int a = 0; a < 2; ++a)
        #pragma unroll
        for (int b2 = 0; b2 < 3; ++b2)
            #pragma unroll
            for (int r = 0; r < 4; ++r) {
                int row = m0 + r0 + a * 16 + kq * 4 + r;
                int col = n0g + c0 + b2 * 16 + mfr;
                qkv[(size_t)row * NQKV + col] = f2bf(acc[a][b2][r]);
            }
}

// ---------------------------------------------------------------------------
// Kernel 1 (fallback, small ws): R2's fused-convert MFMA proj.
// ---------------------------------------------------------------------------
__global__ __launch_bounds__(256) void proj_kernel(
    const float* __restrict__ x,
    const float* __restrict__ Wk,
    const float* __restrict__ Wq,
    const float* __restrict__ Wv,
    unsigned short* __restrict__ qkv)
{
    __shared__ unsigned short Ab[64 * 64];
    __shared__ unsigned short Bb[64 * 64];

    const int m0 = blockIdx.x * 64;
    const int by = blockIdx.y;
    const float* __restrict__ W = (by == 0) ? Wk : ((by == 1) ? Wq : Wv);

    const int t  = threadIdx.x;
    const int wv = t >> 6;
    const int ln = t & 63;
    const int mfr = ln & 15;
    const int kq  = ln >> 4;

    f32x4 acc[4] = {};

    for (int kc = 0; kc < C_DIM; kc += 64) {
        float4 fx[2][2], fw[2][2];
        #pragma unroll
        for (int it = 0; it < 2; ++it) {
            int u   = it * 256 + t;
            int row = u >> 3;
            int k8  = (u & 7) * 8;
            const float* gx = &x[(size_t)(m0 + row) * C_DIM + kc + k8];
            fx[it][0] = *(const float4*)gx;
            fx[it][1] = *(const float4*)(gx + 4);
            const float* gw = &W[(size_t)row * C_DIM + kc + k8];
            fw[it][0] = *(const float4*)gw;
            fw[it][1] = *(const float4*)(gw + 4);
        }
        __syncthreads();
        #pragma unroll
        for (int it = 0; it < 2; ++it) {
            int u   = it * 256 + t;
            int row = u >> 3;
            int k8  = (u & 7) * 8;
            u16x8 av, bv;
            av[0] = f2bf(fx[it][0].x); av[1] = f2bf(fx[it][0].y);
            av[2] = f2bf(fx[it][0].z); av[3] = f2bf(fx[it][0].w);
            av[4] = f2bf(fx[it][1].x); av[5] = f2bf(fx[it][1].y);
            av[6] = f2bf(fx[it][1].z); av[7] = f2bf(fx[it][1].w);
            bv[0] = f2bf(fw[it][0].x); bv[1] = f2bf(fw[it][0].y);
            bv[2] = f2bf(fw[it][0].z); bv[3] = f2bf(fw[it][0].w);
            bv[4] = f2bf(fw[it][1].x); bv[5] = f2bf(fw[it][1].y);
            bv[6] = f2bf(fw[it][1].z); bv[7] = f2bf(fw[it][1].w);
            *(u16x8*)&Ab[row * 64 + k8] = av;
            *(u16x8*)&Bb[row * 64 + k8] = bv;
        }
        __syncthreads();
        #pragma unroll
        for (int ks = 0; ks < 64; ks += 32) {
            bf16x8 af = *(const bf16x8*)&Ab[(wv * 16 + mfr) * 64 + ks + kq * 8];
            #pragma unroll
            for (int ct = 0; ct < 4; ++ct) {
                bf16x8 bfv = *(const bf16x8*)&Bb[(ct * 16 + mfr) * 64 + ks + kq * 8];
                acc[ct] = __builtin_amdgcn_mfma_f32_16x16x32_bf16(af, bfv, acc[ct], 0, 0, 0);
            }
        }
    }
    const int n0 = by * 64;
    #pragma unroll
    for (int ct = 0; ct < 4; ++ct)
        #pragma unroll
        for (int r = 0; r < 4; ++r) {
            int row = m0 + wv * 16 + kq * 4 + r;
            int col = n0 + ct * 16 + mfr;
            qkv[(size_t)row * NQKV + col] = f2bf(acc[ct][r]);
        }
}

// ---------------------------------------------------------------------------
// Kernel 2: sparse BigBird attention, one wave per query row.
// Dedup via per-wave LDS bitmap atomicOr; PV with 8-col groups (u16x8 loads).
// ---------------------------------------------------------------------------
__global__ __launch_bounds__(256) void attn_kernel(
    const unsigned short* __restrict__ qkv,   // bf16 bits [16384][192]
    const int*  __restrict__ rnd,             // [2048][64]
    float* __restrict__ out)                  // [16384][64]
{
    const int wv = threadIdx.x >> 6;
    const int ln = threadIdx.x & 63;
    const int bi = blockIdx.x * 4 + wv;
    const int b  = bi >> 11;
    const int i  = bi & (T_DIM - 1);

    __shared__ float    qs_all[4][64];
    __shared__ int2     cl_all[4][192];
    __shared__ unsigned bm_all[4][64];
    float*    qs = qs_all[wv];
    int2*     cl = cl_all[wv];
    unsigned* bm = bm_all[wv];

    qs[ln] = bf2f(qkv[(size_t)bi * NQKV + 64 + ln]);
    bm[ln] = 0u;

    // candidate columns (clamped so loads are always in-range)
    int  j0 = i - ln;            bool v0 = (j0 >= 0); if (!v0) j0 = 0;
    int  j1 = ln;                bool v1 = (j1 < i - 63);
    int  j2 = rnd[i * 64 + ln];  bool v2 = (j2 < i - 63) && (j2 >= 64);
    if (v2) {   // dedup among randoms: winner of atomicOr keeps the column
        unsigned old = atomicOr(&bm[j2 >> 5], 1u << (j2 & 31));
        v2 = ((old >> (j2 & 31)) & 1u) == 0u;
    }
    __syncthreads();

    // ---- QK^T scores (candidate-parallel, branch-free) ----
    const unsigned short* kb = qkv + (size_t)b * T_DIM * NQKV;
    const unsigned short* k0 = kb + (size_t)j0 * NQKV;
    const unsigned short* k1 = kb + (size_t)j1 * NQKV;
    const unsigned short* k2 = kb + (size_t)j2 * NQKV;
    float s0 = 0.f, s1 = 0.f, s2 = 0.f;
    #pragma unroll
    for (int h = 0; h < H_DIM; h += 8) {
        u16x8 a0 = *(const u16x8*)(k0 + h);
        u16x8 a1 = *(const u16x8*)(k1 + h);
        u16x8 a2 = *(const u16x8*)(k2 + h);
        #pragma unroll
        for (int e = 0; e < 8; ++e) {
            float qv = qs[h + e];
            s0 = fmaf(qv, bf2f(a0[e]), s0);
            s1 = fmaf(qv, bf2f(a1[e]), s1);
            s2 = fmaf(qv, bf2f(a2[e]), s2);
        }
    }
    s0 = v0 ? s0 * 0.125f : -1e30f;
    s1 = v1 ? s1 * 0.125f : -1e30f;
    s2 = v2 ? s2 * 0.125f : -1e30f;

    // ---- softmax over the wave ----
    float mx = fmaxf(s0, fmaxf(s1, s2));
    #pragma unroll
    for (int m = 32; m; m >>= 1) mx = fmaxf(mx, __shfl_xor(mx, m));
    float e0 = v0 ? __expf(s0 - mx) : 0.f;
    float e1 = v1 ? __expf(s1 - mx) : 0.f;
    float e2 = v2 ? __expf(s2 - mx) : 0.f;
    float sum = e0 + e1 + e2;
    #pragma unroll
    for (int m = 32; m; m >>= 1) sum += __shfl_xor(sum, m);

    cl[ln]       = make_int2(j0, __float_as_int(e0));
    cl[64 + ln]  = make_int2(j1, __float_as_int(e1));
    cl[128 + ln] = make_int2(j2, __float_as_int(e2));
    __syncthreads();

    // ---- PV: 8 columns/iter, 8 lanes per column, u16x8 (16B) v loads ----
    const unsigned short* vb = kb + 128;
    const int g  = ln >> 3;          // column group 0..7
    const int q8 = (ln & 7) * 8;     // h base for this lane
    float acc[8] = {};
    #pragma unroll 4
    for (int c = 0; c < 24; ++c) {
        int2 p = cl[c * 8 + g];
        float w = __int_as_float(p.y);
        u16x8 vvv = *(const u16x8*)(vb + (size_t)p.x * NQKV + q8);
        #pragma unroll
        for (int e = 0; e < 8; ++e)
            acc[e] = fmaf(w, bf2f(vvv[e]), acc[e]);
    }
    // reduce across the 8 column groups (lanes sharing q8)
    #pragma unroll
    for (int m = 8; m <= 32; m <<= 1)
        #pragma unroll
        for (int e = 0; e < 8; ++e)
            acc[e] += __shfl_xor(acc[e], m);

    if (ln < 8) {
        float inv = 1.f / sum;
        float* op = &out[(size_t)bi * H_DIM + q8];
        *(float4*)op       = make_float4(acc[0]*inv, acc[1]*inv, acc[2]*inv, acc[3]*inv);
        *(float4*)(op + 4) = make_float4(acc[4]*inv, acc[5]*inv, acc[6]*inv, acc[7]*inv);
    }
}

// ---------------------------------------------------------------------------
extern "C" void kernel_launch(void* const* d_in, const int* in_sizes, int n_in,
                              void* d_out, int out_size, void* d_ws, size_t ws_size,
                              hipStream_t stream) {
    const float* x   = (const float*)d_in[0];
    const int*   rnd = (const int*)  d_in[1];
    const float* Wk  = (const float*)d_in[2];
    const float* Wq  = (const float*)d_in[3];
    const float* Wv  = (const float*)d_in[4];
    float* out = (float*)d_out;

    const size_t xb_elems   = (size_t)M_TOTAL * C_DIM;          // 16.7M
    const size_t wall_elems = (size_t)NQKV * C_DIM;             // 196608
    const size_t qkv_elems  = (size_t)M_TOTAL * NQKV;           // 3.1M
    const size_t need = (xb_elems + wall_elems + qkv_elems) * 2;

    if (ws_size >= need) {
        unsigned short* xb   = (unsigned short*)d_ws;
        unsigned short* Wall = xb + xb_elems;
        unsigned short* qkv  = Wall + wall_elems;
        convert_kernel<<<(X_THREADS + W_THREADS) / 256, 256, 0, stream>>>(
            x, Wk, Wq, Wv, xb, Wall);
        dim3 g1(M_TOTAL / 64, 2);
        proj_glds_kernel<<<g1, 256, 0, stream>>>(xb, Wall, qkv);
        attn_kernel<<<M_TOTAL / 4, 256, 0, stream>>>(qkv, rnd, out);
    } else {
        unsigned short* qkv = (unsigned short*)d_ws;
        dim3 g1(M_TOTAL / 64, 3);
        proj_kernel<<<g1, 256, 0, stream>>>(x, Wk, Wq, Wv, qkv);
        attn_kernel<<<M_TOTAL / 4, 256, 0, stream>>>(qkv, rnd, out);
    }
}

// Round 4
// 189.515 us; speedup vs baseline: 1.7882x; 1.0004x over previous
//
#include <hip/hip_runtime.h>
#include <math.h>

#define T_DIM 2048
#define C_DIM 1024
#define H_DIM 64
#define M_TOTAL 16384            // B*T
#define NQKV 192                 // k(0..63) | q(64..127) | v(128..191)

typedef __bf16 bf16x8 __attribute__((ext_vector_type(8)));
typedef float f32x4 __attribute__((ext_vector_type(4)));
typedef unsigned short u16x8 __attribute__((ext_vector_type(8)));

__device__ __forceinline__ unsigned short f2bf(float f) {
    unsigned u = __float_as_uint(f);
    unsigned r = (u + 0x7FFFu + ((u >> 16) & 1u)) >> 16;   // RNE
    return (unsigned short)r;
}
__device__ __forceinline__ float bf2f(unsigned short u) {
    return __uint_as_float(((unsigned)u) << 16);
}
// pack 2 floats -> 2 bf16 bits (round-half-up): 2x v_add + 1x v_perm
__device__ __forceinline__ unsigned pack_bf2(float f0, float f1) {
    unsigned u0 = __float_as_uint(f0) + 0x8000u;
    unsigned u1 = __float_as_uint(f1) + 0x8000u;
    return __builtin_amdgcn_perm(u1, u0, 0x07060302u);
}
__device__ __forceinline__ uint4 cvt8(float4 a, float4 b) {
    return make_uint4(pack_bf2(a.x, a.y), pack_bf2(a.z, a.w),
                      pack_bf2(b.x, b.y), pack_bf2(b.z, b.w));
}

// ---------------------------------------------------------------------------
// Kernel 1: fused convert + bf16 MFMA QKV projection. One path, ws = qkv only.
// Block: 64 rows x 192 cols (k|q|v in one block -> x converted ONCE), BK=64,
// 512 threads (8 waves), wave tile 32x48 (2x3 MFMA tiles). Grid: 256 = 1/CU.
// LDS k-offset XOR-swizzled by row to break fragment-read bank aliasing.
// ---------------------------------------------------------------------------
__global__ __launch_bounds__(512) void proj_kernel(
    const float* __restrict__ x,
    const float* __restrict__ Wk,
    const float* __restrict__ Wq,
    const float* __restrict__ Wv,
    unsigned short* __restrict__ qkv)   // [16384][192] bf16 bits
{
    __shared__ unsigned short Ab[64 * 64];    // [row][k^swz]
    __shared__ unsigned short Bb[192 * 64];   // [col][k^swz]

    const int m0 = blockIdx.x * 64;
    const int t  = threadIdx.x;
    const int wv = t >> 6, ln = t & 63;
    const int mfr = ln & 15, kq = ln >> 4;
    const int r0 = (wv & 1) * 32;            // wave row base
    const int c0 = (wv >> 1) * 48;           // wave col base (0..144)

    // staging assignment: thread -> row (t>>3), k-octet (t&7)
    const int srow  = t >> 3;                // 0..63
    const int sk8   = (t & 7) * 8;
    const int skoff = sk8 ^ ((srow & 7) * 8);

    const float* gp[4] = {
        x  + (size_t)(m0 + srow) * C_DIM + sk8,
        Wk + (size_t)srow * C_DIM + sk8,
        Wq + (size_t)srow * C_DIM + sk8,
        Wv + (size_t)srow * C_DIM + sk8 };
    unsigned short* lp[4] = {
        &Ab[srow * 64 + skoff],
        &Bb[srow * 64 + skoff],
        &Bb[(srow + 64) * 64 + skoff],
        &Bb[(srow + 128) * 64 + skoff] };

    f32x4 acc[2][3] = {};

    // prefetch chunk 0
    float4 ra[4], rb[4];
    #pragma unroll
    for (int s = 0; s < 4; ++s) {
        ra[s] = *(const float4*)(gp[s]);
        rb[s] = *(const float4*)(gp[s] + 4);
    }

    for (int kc = 0; kc < C_DIM; kc += 64) {
        __syncthreads();   // all waves done reading previous chunk's LDS
        #pragma unroll
        for (int s = 0; s < 4; ++s)
            *(uint4*)lp[s] = cvt8(ra[s], rb[s]);
        // prefetch next chunk (register dest: no barrier drain required)
        if (kc + 64 < C_DIM) {
            #pragma unroll
            for (int s = 0; s < 4; ++s) {
                ra[s] = *(const float4*)(gp[s] + kc + 64);
                rb[s] = *(const float4*)(gp[s] + kc + 68);
            }
        }
        __syncthreads();   // LDS filled
        #pragma unroll
        for (int ks = 0; ks < 64; ks += 32) {
            bf16x8 af[2], bf[3];
            #pragma unroll
            for (int a = 0; a < 2; ++a) {
                int row = r0 + a * 16 + mfr;
                af[a] = *(const bf16x8*)&Ab[row * 64 + ((ks + kq * 8) ^ ((row & 7) * 8))];
            }
            #pragma unroll
            for (int b2 = 0; b2 < 3; ++b2) {
                int row = c0 + b2 * 16 + mfr;
                bf[b2] = *(const bf16x8*)&Bb[row * 64 + ((ks + kq * 8) ^ ((row & 7) * 8))];
            }
            #pragma unroll
            for (int a = 0; a < 2; ++a)
                #pragma unroll
                for (int b2 = 0; b2 < 3; ++b2)
                    acc[a][b2] = __builtin_amdgcn_mfma_f32_16x16x32_bf16(
                        af[a], bf[b2], acc[a][b2], 0, 0, 0);
        }
    }

    // epilogue: C layout col=lane&15, row=(lane>>4)*4+reg
    #pragma unroll
    for (int a = 0; a < 2; ++a)
        #pragma unroll
        for (int b2 = 0; b2 < 3; ++b2)
            #pragma unroll
            for (int r = 0; r < 4; ++r) {
                int row = m0 + r0 + a * 16 + kq * 4 + r;
                int col = c0 + b2 * 16 + mfr;
                qkv[(size_t)row * NQKV + col] = f2bf(acc[a][b2][r]);
            }
}

// ---------------------------------------------------------------------------
// Kernel 2: sparse BigBird attention, one wave per query row.
// Dedup via per-wave LDS bitmap atomicOr; vectorized qs reads; PV batched
// (8 in-flight gathers) to break the ds_read->global_load dependency chain.
// ---------------------------------------------------------------------------
__global__ __launch_bounds__(256) void attn_kernel(
    const unsigned short* __restrict__ qkv,   // bf16 bits [16384][192]
    const int*  __restrict__ rnd,             // [2048][64]
    float* __restrict__ out)                  // [16384][64]
{
    const int wv = threadIdx.x >> 6;
    const int ln = threadIdx.x & 63;
    const int bi = blockIdx.x * 4 + wv;
    const int b  = bi >> 11;
    const int i  = bi & (T_DIM - 1);

    __shared__ float    qs_all[4][64];
    __shared__ int2     cl_all[4][192];
    __shared__ unsigned bm_all[4][64];
    float*    qs = qs_all[wv];
    int2*     cl = cl_all[wv];
    unsigned* bm = bm_all[wv];

    qs[ln] = bf2f(qkv[(size_t)bi * NQKV + 64 + ln]);
    bm[ln] = 0u;

    // candidate columns (clamped so loads are always in-range)
    int  j0 = i - ln;            bool v0 = (j0 >= 0); if (!v0) j0 = 0;
    int  j1 = ln;                bool v1 = (j1 < i - 63);
    int  j2 = rnd[i * 64 + ln];  bool v2 = (j2 < i - 63) && (j2 >= 64);
    if (v2) {   // dedup among randoms: winner of atomicOr keeps the column
        unsigned old = atomicOr(&bm[j2 >> 5], 1u << (j2 & 31));
        v2 = ((old >> (j2 & 31)) & 1u) == 0u;
    }
    __syncthreads();

    // ---- QK^T scores (candidate-parallel, branch-free) ----
    const unsigned short* kb = qkv + (size_t)b * T_DIM * NQKV;
    const unsigned short* k0 = kb + (size_t)j0 * NQKV;
    const unsigned short* k1 = kb + (size_t)j1 * NQKV;
    const unsigned short* k2 = kb + (size_t)j2 * NQKV;
    float s0 = 0.f, s1 = 0.f, s2 = 0.f;
    #pragma unroll
    for (int h = 0; h < H_DIM; h += 8) {
        u16x8 a0 = *(const u16x8*)(k0 + h);
        u16x8 a1 = *(const u16x8*)(k1 + h);
        u16x8 a2 = *(const u16x8*)(k2 + h);
        f32x4 qa = *(const f32x4*)&qs[h];
        f32x4 qb = *(const f32x4*)&qs[h + 4];
        float qv[8] = {qa[0], qa[1], qa[2], qa[3], qb[0], qb[1], qb[2], qb[3]};
        #pragma unroll
        for (int e = 0; e < 8; ++e) {
            s0 = fmaf(qv[e], bf2f(a0[e]), s0);
            s1 = fmaf(qv[e], bf2f(a1[e]), s1);
            s2 = fmaf(qv[e], bf2f(a2[e]), s2);
        }
    }
    s0 = v0 ? s0 * 0.125f : -1e30f;
    s1 = v1 ? s1 * 0.125f : -1e30f;
    s2 = v2 ? s2 * 0.125f : -1e30f;

    // ---- softmax over the wave ----
    float mx = fmaxf(s0, fmaxf(s1, s2));
    #pragma unroll
    for (int m = 32; m; m >>= 1) mx = fmaxf(mx, __shfl_xor(mx, m));
    float e0 = v0 ? __expf(s0 - mx) : 0.f;
    float e1 = v1 ? __expf(s1 - mx) : 0.f;
    float e2 = v2 ? __expf(s2 - mx) : 0.f;
    float sum = e0 + e1 + e2;
    #pragma unroll
    for (int m = 32; m; m >>= 1) sum += __shfl_xor(sum, m);

    cl[ln]       = make_int2(j0, __float_as_int(e0));
    cl[64 + ln]  = make_int2(j1, __float_as_int(e1));
    cl[128 + ln] = make_int2(j2, __float_as_int(e2));
    __syncthreads();

    // ---- PV: batched for ILP. 8 lanes/col, u16x8 (16B) v loads ----
    const unsigned short* vb = kb + 128;
    const int g  = ln >> 3;          // column group 0..7
    const int q8 = (ln & 7) * 8;     // h base for this lane
    float acc[8] = {};
    #pragma unroll
    for (int bt = 0; bt < 3; ++bt) {
        int2 p[8];
        #pragma unroll
        for (int c = 0; c < 8; ++c) p[c] = cl[(bt * 8 + c) * 8 + g];
        u16x8 vvv[8];
        #pragma unroll
        for (int c = 0; c < 8; ++c)
            vvv[c] = *(const u16x8*)(vb + (size_t)p[c].x * NQKV + q8);
        #pragma unroll
        for (int c = 0; c < 8; ++c) {
            float w = __int_as_float(p[c].y);
            #pragma unroll
            for (int e = 0; e < 8; ++e)
                acc[e] = fmaf(w, bf2f(vvv[c][e]), acc[e]);
        }
    }
    // reduce across the 8 column groups (lanes sharing q8)
    #pragma unroll
    for (int m = 8; m <= 32; m <<= 1)
        #pragma unroll
        for (int e = 0; e < 8; ++e)
            acc[e] += __shfl_xor(acc[e], m);

    if (ln < 8) {
        float inv = 1.f / sum;
        float* op = &out[(size_t)bi * H_DIM + q8];
        *(float4*)op       = make_float4(acc[0]*inv, acc[1]*inv, acc[2]*inv, acc[3]*inv);
        *(float4*)(op + 4) = make_float4(acc[4]*inv, acc[5]*inv, acc[6]*inv, acc[7]*inv);
    }
}

// ---------------------------------------------------------------------------
extern "C" void kernel_launch(void* const* d_in, const int* in_sizes, int n_in,
                              void* d_out, int out_size, void* d_ws, size_t ws_size,
                              hipStream_t stream) {
    const float* x   = (const float*)d_in[0];
    const int*   rnd = (const int*)  d_in[1];
    const float* Wk  = (const float*)d_in[2];
    const float* Wq  = (const float*)d_in[3];
    const float* Wv  = (const float*)d_in[4];
    float* out = (float*)d_out;
    unsigned short* qkv = (unsigned short*)d_ws;   // 16384*192*2 = 6.3 MB

    proj_kernel<<<M_TOTAL / 64, 512, 0, stream>>>(x, Wk, Wq, Wv, qkv);
    attn_kernel<<<M_TOTAL / 4, 256, 0, stream>>>(qkv, rnd, out);
}

// Round 5
// 150.499 us; speedup vs baseline: 2.2518x; 1.2592x over previous
//
#include <hip/hip_runtime.h>
#include <math.h>

#define T_DIM 2048
#define C_DIM 1024
#define H_DIM 64
#define M_TOTAL 16384            // B*T
#define NQKV 192                 // k(0..63) | q(64..127) | v(128..191)

typedef __bf16 bf16x8 __attribute__((ext_vector_type(8)));
typedef float f32x4 __attribute__((ext_vector_type(4)));
typedef unsigned short u16x8 __attribute__((ext_vector_type(8)));

__device__ __forceinline__ unsigned short f2bf(float f) {
    unsigned u = __float_as_uint(f);
    unsigned r = (u + 0x7FFFu + ((u >> 16) & 1u)) >> 16;   // RNE
    return (unsigned short)r;
}
__device__ __forceinline__ float bf2f(unsigned short u) {
    return __uint_as_float(((unsigned)u) << 16);
}
// pack 2 floats -> 2 bf16 bits (round-half-up): 2x v_add + 1x v_perm
__device__ __forceinline__ unsigned pack_bf2(float f0, float f1) {
    unsigned u0 = __float_as_uint(f0) + 0x8000u;
    unsigned u1 = __float_as_uint(f1) + 0x8000u;
    return __builtin_amdgcn_perm(u1, u0, 0x07060302u);
}
__device__ __forceinline__ uint4 cvt8(float4 a, float4 b) {
    return make_uint4(pack_bf2(a.x, a.y), pack_bf2(a.z, a.w),
                      pack_bf2(b.x, b.y), pack_bf2(b.z, b.w));
}

// ---------------------------------------------------------------------------
// Kernel 1: fused convert + bf16 MFMA QKV projection (unchanged from R4).
// Block: 64 rows x 192 cols, BK=64, 512 threads, wave tile 32x48.
// ---------------------------------------------------------------------------
__global__ __launch_bounds__(512) void proj_kernel(
    const float* __restrict__ x,
    const float* __restrict__ Wk,
    const float* __restrict__ Wq,
    const float* __restrict__ Wv,
    unsigned short* __restrict__ qkv)   // [16384][192] bf16 bits
{
    __shared__ unsigned short Ab[64 * 64];    // [row][k^swz]
    __shared__ unsigned short Bb[192 * 64];   // [col][k^swz]

    const int m0 = blockIdx.x * 64;
    const int t  = threadIdx.x;
    const int wv = t >> 6, ln = t & 63;
    const int mfr = ln & 15, kq = ln >> 4;
    const int r0 = (wv & 1) * 32;
    const int c0 = (wv >> 1) * 48;

    const int srow  = t >> 3;                // 0..63
    const int sk8   = (t & 7) * 8;
    const int skoff = sk8 ^ ((srow & 7) * 8);

    const float* gp[4] = {
        x  + (size_t)(m0 + srow) * C_DIM + sk8,
        Wk + (size_t)srow * C_DIM + sk8,
        Wq + (size_t)srow * C_DIM + sk8,
        Wv + (size_t)srow * C_DIM + sk8 };
    unsigned short* lp[4] = {
        &Ab[srow * 64 + skoff],
        &Bb[srow * 64 + skoff],
        &Bb[(srow + 64) * 64 + skoff],
        &Bb[(srow + 128) * 64 + skoff] };

    f32x4 acc[2][3] = {};

    float4 ra[4], rb[4];
    #pragma unroll
    for (int s = 0; s < 4; ++s) {
        ra[s] = *(const float4*)(gp[s]);
        rb[s] = *(const float4*)(gp[s] + 4);
    }

    for (int kc = 0; kc < C_DIM; kc += 64) {
        __syncthreads();
        #pragma unroll
        for (int s = 0; s < 4; ++s)
            *(uint4*)lp[s] = cvt8(ra[s], rb[s]);
        if (kc + 64 < C_DIM) {
            #pragma unroll
            for (int s = 0; s < 4; ++s) {
                ra[s] = *(const float4*)(gp[s] + kc + 64);
                rb[s] = *(const float4*)(gp[s] + kc + 68);
            }
        }
        __syncthreads();
        #pragma unroll
        for (int ks = 0; ks < 64; ks += 32) {
            bf16x8 af[2], bf[3];
            #pragma unroll
            for (int a = 0; a < 2; ++a) {
                int row = r0 + a * 16 + mfr;
                af[a] = *(const bf16x8*)&Ab[row * 64 + ((ks + kq * 8) ^ ((row & 7) * 8))];
            }
            #pragma unroll
            for (int b2 = 0; b2 < 3; ++b2) {
                int row = c0 + b2 * 16 + mfr;
                bf[b2] = *(const bf16x8*)&Bb[row * 64 + ((ks + kq * 8) ^ ((row & 7) * 8))];
            }
            #pragma unroll
            for (int a = 0; a < 2; ++a)
                #pragma unroll
                for (int b2 = 0; b2 < 3; ++b2)
                    acc[a][b2] = __builtin_amdgcn_mfma_f32_16x16x32_bf16(
                        af[a], bf[b2], acc[a][b2], 0, 0, 0);
        }
    }

    #pragma unroll
    for (int a = 0; a < 2; ++a)
        #pragma unroll
        for (int b2 = 0; b2 < 3; ++b2)
            #pragma unroll
            for (int r = 0; r < 4; ++r) {
                int row = m0 + r0 + a * 16 + kq * 4 + r;
                int col = c0 + b2 * 16 + mfr;
                qkv[(size_t)row * NQKV + col] = f2bf(acc[a][b2][r]);
            }
}

// ---------------------------------------------------------------------------
// Kernel 2: sparse BigBird attention. One wave per row, barrier-free
// (all LDS state is per-wave; same-wave DS ordering).
//  - XCD swizzle: batch = blockIdx & 7 -> all of a batch's gathers hit one L2
//  - QK group-gather: 8 lanes per k-row (16B each) -> 8 lines/instr, not 64
//  - PV as R4 (already 8 lines/instr)
// ---------------------------------------------------------------------------
__global__ __launch_bounds__(256) void attn_kernel(
    const unsigned short* __restrict__ qkv,   // bf16 bits [16384][192]
    const int*  __restrict__ rnd,             // [2048][64]
    float* __restrict__ out)                  // [16384][64]
{
    const int wv = threadIdx.x >> 6;
    const int ln = threadIdx.x & 63;
    const int b  = blockIdx.x & 7;                  // XCD-locality swizzle
    const int i  = ((blockIdx.x >> 3) << 2) + wv;   // 0..2047
    const int bi = b * T_DIM + i;

    __shared__ int2     cl_all[4][192];   // (col, score/weight bits)
    __shared__ unsigned bm_all[4][64];
    int2*     cl = cl_all[wv];
    unsigned* bm = bm_all[wv];

    bm[ln] = 0u;

    // ---- candidate table (validity stays in registers) ----
    int  j0 = i - ln;            bool v0 = (j0 >= 0); if (!v0) j0 = 0;
    int  j1 = ln;                bool v1 = (j1 < i - 63);
    int  j2 = rnd[i * 64 + ln];  bool v2 = (j2 < i - 63) && (j2 >= 64);
    if (v2) {   // dedup among randoms: winner of atomicOr keeps the column
        unsigned old = atomicOr(&bm[j2 >> 5], 1u << (j2 & 31));
        v2 = ((old >> (j2 & 31)) & 1u) == 0u;
    }
    cl[ln]       = make_int2(j0, 0);
    cl[64 + ln]  = make_int2(j1, 0);
    cl[128 + ln] = make_int2(j2, 0);

    // ---- q h-slice in registers (8-way same-address load broadcasts) ----
    const int e8 = (ln & 7) * 8;     // h-slice base for this lane
    const int gg = ln >> 3;          // row-within-instruction group 0..7
    u16x8 qraw = *(const u16x8*)(qkv + (size_t)bi * NQKV + 64 + e8);
    float qr[8];
    #pragma unroll
    for (int e = 0; e < 8; ++e) qr[e] = bf2f(qraw[e]);

    const unsigned short* kb = qkv + (size_t)b * T_DIM * NQKV;

    // ---- QK: 8 k-rows per wave64 instruction, batched 4 for MLP ----
    #pragma unroll
    for (int n = 0; n < 24; n += 4) {
        int jj[4];
        #pragma unroll
        for (int u = 0; u < 4; ++u) jj[u] = cl[(n + u) * 8 + gg].x;
        u16x8 kv[4];
        #pragma unroll
        for (int u = 0; u < 4; ++u)
            kv[u] = *(const u16x8*)(kb + (size_t)jj[u] * NQKV + e8);
        #pragma unroll
        for (int u = 0; u < 4; ++u) {
            float p = 0.f;
            #pragma unroll
            for (int e = 0; e < 8; ++e) p = fmaf(qr[e], bf2f(kv[u][e]), p);
            p += __shfl_xor(p, 1);
            p += __shfl_xor(p, 2);
            p += __shfl_xor(p, 4);
            if ((ln & 7) == 0) cl[(n + u) * 8 + gg].y = __float_as_int(p);
        }
    }

    // ---- softmax over this lane's 3 candidates (same-wave DS ordering) ----
    float s0 = __int_as_float(cl[ln].y);
    float s1 = __int_as_float(cl[64 + ln].y);
    float s2 = __int_as_float(cl[128 + ln].y);
    s0 = v0 ? s0 * 0.125f : -1e30f;
    s1 = v1 ? s1 * 0.125f : -1e30f;
    s2 = v2 ? s2 * 0.125f : -1e30f;

    float mx = fmaxf(s0, fmaxf(s1, s2));
    #pragma unroll
    for (int m = 32; m; m >>= 1) mx = fmaxf(mx, __shfl_xor(mx, m));
    float e0 = v0 ? __expf(s0 - mx) : 0.f;
    float e1 = v1 ? __expf(s1 - mx) : 0.f;
    float e2 = v2 ? __expf(s2 - mx) : 0.f;
    float sum = e0 + e1 + e2;
    #pragma unroll
    for (int m = 32; m; m >>= 1) sum += __shfl_xor(sum, m);

    cl[ln].y       = __float_as_int(e0);
    cl[64 + ln].y  = __float_as_int(e1);
    cl[128 + ln].y = __float_as_int(e2);

    // ---- PV: 8 lanes per column (16B each), batched 8, same gg/e8 ----
    const unsigned short* vb = kb + 128;
    float acc[8] = {};
    #pragma unroll
    for (int bt = 0; bt < 3; ++bt) {
        int2 p[8];
        #pragma unroll
        for (int c = 0; c < 8; ++c) p[c] = cl[(bt * 8 + c) * 8 + gg];
        u16x8 vvv[8];
        #pragma unroll
        for (int c = 0; c < 8; ++c)
            vvv[c] = *(const u16x8*)(vb + (size_t)p[c].x * NQKV + e8);
        #pragma unroll
        for (int c = 0; c < 8; ++c) {
            float w = __int_as_float(p[c].y);
            #pragma unroll
            for (int e = 0; e < 8; ++e)
                acc[e] = fmaf(w, bf2f(vvv[c][e]), acc[e]);
        }
    }
    // reduce across the 8 row-groups (lanes sharing e8 differ in bits 3..5)
    #pragma unroll
    for (int m = 8; m <= 32; m <<= 1)
        #pragma unroll
        for (int e = 0; e < 8; ++e)
            acc[e] += __shfl_xor(acc[e], m);

    if (ln < 8) {
        float inv = 1.f / sum;
        float* op = &out[(size_t)bi * H_DIM + e8];
        *(float4*)op       = make_float4(acc[0]*inv, acc[1]*inv, acc[2]*inv, acc[3]*inv);
        *(float4*)(op + 4) = make_float4(acc[4]*inv, acc[5]*inv, acc[6]*inv, acc[7]*inv);
    }
}

// ---------------------------------------------------------------------------
extern "C" void kernel_launch(void* const* d_in, const int* in_sizes, int n_in,
                              void* d_out, int out_size, void* d_ws, size_t ws_size,
                              hipStream_t stream) {
    const float* x   = (const float*)d_in[0];
    const int*   rnd = (const int*)  d_in[1];
    const float* Wk  = (const float*)d_in[2];
    const float* Wq  = (const float*)d_in[3];
    const float* Wv  = (const float*)d_in[4];
    float* out = (float*)d_out;
    unsigned short* qkv = (unsigned short*)d_ws;   // 16384*192*2 = 6.3 MB

    proj_kernel<<<M_TOTAL / 64, 512, 0, stream>>>(x, Wk, Wq, Wv, qkv);
    attn_kernel<<<M_TOTAL / 4, 256, 0, stream>>>(qkv, rnd, out);
}